// Round 1
// baseline (649.375 us; speedup 1.0000x reference)
//
#include <hip/hip_runtime.h>
#include <cstdint>
#include <math.h>

#define F_IN 512
#define HID  16
#define NCLS 40
#define OUT_STRIDE 20

// ---------------- deg / dinv ----------------
__global__ void k_zero(int* __restrict__ p, int n) {
    int i = blockIdx.x * blockDim.x + threadIdx.x;
    if (i < n) p[i] = 0;
}

__global__ void k_hist(const int* __restrict__ dst, int* __restrict__ deg, int E) {
    int e = blockIdx.x * blockDim.x + threadIdx.x;
    if (e < E) atomicAdd(&deg[dst[e]], 1);
}

__global__ void k_dinv(const int* __restrict__ deg, float* __restrict__ dinv, int n) {
    int i = blockIdx.x * blockDim.x + threadIdx.x;
    if (i < n) dinv[i] = rsqrtf((float)deg[i] + 1.0f);  // +1 = self loop
}

// ---------------- block scan (exclusive prefix over deg) ----------------
__global__ void k_scan_a(const int* __restrict__ deg, int* __restrict__ excl,
                         int* __restrict__ bsum, int n) {
    __shared__ int s[256];
    int t = threadIdx.x;
    int i = blockIdx.x * 256 + t;
    int v = (i < n) ? deg[i] : 0;
    s[t] = v;
    __syncthreads();
    for (int off = 1; off < 256; off <<= 1) {
        int tmp = (t >= off) ? s[t - off] : 0;
        __syncthreads();
        s[t] += tmp;
        __syncthreads();
    }
    if (i < n) excl[i] = s[t] - v;
    if (t == 255) bsum[blockIdx.x] = s[t];
}

__global__ void k_scan_b(const int* __restrict__ bsum, int* __restrict__ boff, int nb) {
    __shared__ int s[512];
    int t = threadIdx.x;
    int v = (t < nb) ? bsum[t] : 0;
    s[t] = v;
    __syncthreads();
    for (int off = 1; off < 512; off <<= 1) {
        int tmp = (t >= off) ? s[t - off] : 0;
        __syncthreads();
        s[t] += tmp;
        __syncthreads();
    }
    if (t < nb) boff[t] = s[t] - v;
}

__global__ void k_scan_c(int* __restrict__ excl, const int* __restrict__ boff,
                         int* __restrict__ fpos, int n, int Etot) {
    int i = blockIdx.x * 256 + threadIdx.x;
    if (i < n) {
        int v = excl[i] + boff[blockIdx.x];
        excl[i] = v;
        fpos[i] = v;
        if (i == n - 1) excl[n] = Etot;
    }
}

// ---------------- CSR fill (src values bucketed by dst) ----------------
__global__ void k_fill(const int* __restrict__ src, const int* __restrict__ dst,
                       int* __restrict__ fpos, int* __restrict__ csr, int E) {
    int e = blockIdx.x * blockDim.x + threadIdx.x;
    if (e < E) {
        int d = dst[e];
        int p = atomicAdd(&fpos[d], 1);
        csr[p] = src[e];
    }
}

// ---------------- GEMM1: h1s[i][c] = (x[i] . W1[:,c]) * dinv[i] ----------------
#define RPT 8  // rows per thread
__global__ __launch_bounds__(256) void k_gemm1(const float* __restrict__ x,
                                               const float* __restrict__ W1,
                                               const float* __restrict__ dinv,
                                               float* __restrict__ h1s, int n) {
    __shared__ float w[F_IN * HID];  // 32 KB
    int t = threadIdx.x;
    for (int i = t * 4; i < F_IN * HID; i += 256 * 4)
        *(float4*)&w[i] = *(const float4*)&W1[i];
    __syncthreads();

    int c = t & 15;          // column 0..15  (lanes 0-15 share rows -> x broadcast)
    int g = t >> 4;          // row group 0..15
    int row0 = (blockIdx.x * 16 + g) * RPT;

    const float* xp[RPT];
#pragma unroll
    for (int r = 0; r < RPT; r++) {
        int rr = row0 + r;
        if (rr >= n) rr = n - 1;  // clamp; garbage acc, store guarded below
        xp[r] = x + (size_t)rr * F_IN;
    }

    float acc[RPT];
#pragma unroll
    for (int r = 0; r < RPT; r++) acc[r] = 0.f;

    for (int k4 = 0; k4 < F_IN / 4; k4++) {
        float4 xv[RPT];
#pragma unroll
        for (int r = 0; r < RPT; r++) xv[r] = *(const float4*)&xp[r][k4 * 4];
#pragma unroll
        for (int kk = 0; kk < 4; kk++) {
            float wv = w[(k4 * 4 + kk) * HID + c];
#pragma unroll
            for (int r = 0; r < RPT; r++)
                acc[r] = fmaf(((const float*)&xv[r])[kk], wv, acc[r]);
        }
    }

#pragma unroll
    for (int r = 0; r < RPT; r++) {
        int rr = row0 + r;
        if (rr < n) h1s[rr * HID + c] = acc[r] * dinv[rr];
    }
}

// ---------------- layer1 aggregation + bias + relu + pre-scale ----------------
// z[d][c] = relu(dinv[d]*(sum_{s->d} h1s[s][c] + h1s[d][c]) + b1[c]) * dinv[d]
__global__ void k_agg1(const float* __restrict__ h1s, const int* __restrict__ csr,
                       const int* __restrict__ roff, const float* __restrict__ dinv,
                       const float* __restrict__ b1, float* __restrict__ z, int n) {
    int t = threadIdx.x;
    int c = t & 15;
    int node = blockIdx.x * 16 + (t >> 4);
    if (node >= n) return;
    int s0 = roff[node], s1 = roff[node + 1];
    float sum = h1s[node * HID + c];  // self loop
    for (int j = s0; j < s1; j++) {
        int s = csr[j];
        sum += h1s[s * HID + c];
    }
    float dv = dinv[node];
    float pre = dv * sum + b1[c];
    z[node * HID + c] = fmaxf(pre, 0.f) * dv;
}

// ---------------- layer2 (selected rows only) + log_softmax ----------------
// out[r] = log_softmax( dinv[i]*(sum_{s->i} z[s] + z[i]) @ W2 + b2 ),  i = 20r
__global__ void k_out(const float* __restrict__ z, const int* __restrict__ csr,
                      const int* __restrict__ roff, const float* __restrict__ dinv,
                      const float* __restrict__ W2, const float* __restrict__ b2,
                      float* __restrict__ out, int nOut) {
    int lane = threadIdx.x & 63;
    int wv = (blockIdx.x * blockDim.x + threadIdx.x) >> 6;  // one wave per out row
    if (wv >= nOut) return;
    int node = wv * OUT_STRIDE;
    int c = lane & 15, sub = lane >> 4;
    int s0 = roff[node], s1 = roff[node + 1];
    float sum = 0.f;
    for (int j = s0 + sub; j < s1; j += 4) sum += z[csr[j] * HID + c];
    sum += __shfl_xor(sum, 16);
    sum += __shfl_xor(sum, 32);
    sum += z[node * HID + c];  // self loop
    float a = dinv[node] * sum;

    int jj = lane < NCLS ? lane : 0;
    float v = 0.f;
#pragma unroll
    for (int cc = 0; cc < 16; cc++) {
        float ac = __shfl(a, cc);  // lane cc holds column cc (sub==0)
        v = fmaf(ac, W2[cc * NCLS + jj], v);
    }
    v += b2[jj];

    float vm = lane < NCLS ? v : -INFINITY;
    for (int off = 1; off < 64; off <<= 1) vm = fmaxf(vm, __shfl_xor(vm, off));
    float ex = lane < NCLS ? expf(v - vm) : 0.f;
    float se = ex;
    for (int off = 1; off < 64; off <<= 1) se += __shfl_xor(se, off);
    float ls = logf(se);
    if (lane < NCLS) out[wv * NCLS + lane] = v - vm - ls;
}

// ---------------- host launcher ----------------
extern "C" void kernel_launch(void* const* d_in, const int* in_sizes, int n_in,
                              void* d_out, int out_size, void* d_ws, size_t ws_size,
                              hipStream_t stream) {
    const int E = in_sizes[0] / 2;
    const int N = in_sizes[1] / F_IN;
    const int nOut = (N + OUT_STRIDE - 1) / OUT_STRIDE;

    const int* src = (const int*)d_in[0];
    const int* dst = src + E;
    const float* x  = (const float*)d_in[1];
    const float* W1 = (const float*)d_in[2];
    const float* b1 = (const float*)d_in[3];
    const float* W2 = (const float*)d_in[4];
    const float* b2 = (const float*)d_in[5];
    float* out = (float*)d_out;

    // workspace carve (16B aligned)
    uint8_t* w = (uint8_t*)d_ws;
    size_t off = 0;
    auto carve = [&](size_t bytes) {
        void* p = w + off;
        off += (bytes + 15) & ~(size_t)15;
        return p;
    };
    int*   deg  = (int*)carve((size_t)N * 4);
    float* dinv = (float*)carve((size_t)N * 4);
    int*   roff = (int*)carve((size_t)(N + 1) * 4);
    int*   fpos = (int*)carve((size_t)N * 4);
    int*   bsum = (int*)carve(512 * 4);
    int*   boff = (int*)carve(512 * 4);
    int*   csr  = (int*)carve((size_t)E * 4);
    float* h1s  = (float*)carve((size_t)N * HID * 4);
    float* z    = (float*)carve((size_t)N * HID * 4);
    (void)ws_size; (void)n_in; (void)out_size;

    const int nbN = (N + 255) / 256;     // 391 (<=512 required for scan_b)
    const int nbE = (E + 255) / 256;

    k_zero<<<nbN, 256, 0, stream>>>(deg, N);
    k_hist<<<nbE, 256, 0, stream>>>(dst, deg, E);
    k_dinv<<<nbN, 256, 0, stream>>>(deg, dinv, N);
    k_scan_a<<<nbN, 256, 0, stream>>>(deg, roff, bsum, N);
    k_scan_b<<<1, 512, 0, stream>>>(bsum, boff, nbN);
    k_scan_c<<<nbN, 256, 0, stream>>>(roff, boff, fpos, N, E);
    k_fill<<<nbE, 256, 0, stream>>>(src, dst, fpos, csr, E);
    k_gemm1<<<(N + 16 * RPT - 1) / (16 * RPT), 256, 0, stream>>>(x, W1, dinv, h1s, N);
    k_agg1<<<(N + 15) / 16, 256, 0, stream>>>(h1s, csr, roff, dinv, b1, z, N);
    k_out<<<(nOut * 64 + 255) / 256, 256, 0, stream>>>(z, csr, roff, dinv, W2, b2, out, nOut);
}